// Round 1
// baseline (202.680 us; speedup 1.0000x reference)
//
#include <hip/hip_runtime.h>
#include <math.h>

#define HW4    19200        // (240*320)/4 float4 per channel
#define NCH    86
#define OCH    89
#define NB     4
#define THRESHF 0.7f
#define BIGF   1e30f

// ws float layout:
// [0..63]    votes: b*16 + j*7 + {0:denom, 1..3:loc, 4..6:rot}
// [64..207]  M:     (b*3 + k)*12 row-major 3x4 [R|t]
// [256..279] minmax keys (uint32): b*6 + c   (0..2 low, 3..5 up)
// [288..319] prep:  b*8 + {0..2 low, 3 safe, 4 flag}

__device__ __forceinline__ float sigmoidf_(float x) {
    if (x >= 0.f) { return 1.f / (1.f + expf(-x)); }
    float e = expf(x); return e / (1.f + e);
}
__device__ __forceinline__ unsigned fkey(float f) {
    unsigned u = __float_as_uint(f);
    return (u & 0x80000000u) ? ~u : (u | 0x80000000u);
}
__device__ __forceinline__ float funkey(unsigned k) {
    unsigned u = (k & 0x80000000u) ? (k ^ 0x80000000u) : ~k;
    return __uint_as_float(u);
}

__global__ __launch_bounds__(256) void k_votes(const float4* __restrict__ in4,
                                               float* __restrict__ ws) {
    const int b = blockIdx.y;
    const int t = blockIdx.x * 256 + threadIdx.x;
    const size_t ib = (size_t)b * NCH * HW4 + t;
    float4 mv = in4[ib + (size_t)3 * HW4];
    float4 c0 = in4[ib + (size_t)20 * HW4];
    float4 c1 = in4[ib + (size_t)21 * HW4];
    float4 L[12];
#pragma unroll
    for (int i = 0; i < 12; i++) L[i] = in4[ib + (size_t)(4 + i) * HW4];
    float acc[14];
#pragma unroll
    for (int i = 0; i < 14; i++) acc[i] = 0.f;
    const float* mvf = (const float*)&mv;
    const float* c0f = (const float*)&c0;
    const float* c1f = (const float*)&c1;
#pragma unroll
    for (int k = 0; k < 4; k++) {
        float m  = sigmoidf_(mvf[k]);
        float s0 = sigmoidf_(c0f[k]) * m;
        float s1 = sigmoidf_(c1f[k]) * m;
        float w0 = m * s0, w1 = m * s1;
        acc[0] += s0; acc[7] += s1;
#pragma unroll
        for (int c = 0; c < 3; c++) {
            acc[1 + c]  += ((const float*)&L[c])[k]     * w0;  // loc j0: ch4..6
            acc[8 + c]  += ((const float*)&L[3 + c])[k] * w1;  // loc j1: ch7..9
            acc[4 + c]  += ((const float*)&L[6 + c])[k] * w0;  // rot j0: ch10..12
            acc[11 + c] += ((const float*)&L[9 + c])[k] * w1;  // rot j1: ch13..15
        }
    }
    __shared__ float red[4][14];
    int lane = threadIdx.x & 63, wid = threadIdx.x >> 6;
#pragma unroll
    for (int i = 0; i < 14; i++) {
        float v = acc[i];
        for (int off = 32; off > 0; off >>= 1) v += __shfl_down(v, off, 64);
        if (lane == 0) red[wid][i] = v;
    }
    __syncthreads();
    if (threadIdx.x < 14) {
        float s = red[0][threadIdx.x] + red[1][threadIdx.x] +
                  red[2][threadIdx.x] + red[3][threadIdx.x];
        atomicAdd(&ws[b * 16 + threadIdx.x], s);
    }
}

__global__ void k_build(float* __restrict__ ws) {
    int tid = threadIdx.x;
    if (tid < 12) {
        int b = tid / 3, k = tid % 3;
        float lp0 = 0, lp1 = 0, lp2 = 0, rp0 = 0, rp1 = 0, rp2 = 0;
        if (k > 0) {
            const float* v = ws + b * 16 + (k - 1) * 7;
            float d = v[0] + 1e-5f;
            lp0 = v[1] / d; lp1 = v[2] / d; lp2 = v[3] / d;
            rp0 = v[4] / d; rp1 = v[5] / d; rp2 = v[6] / d;
        }
        float rx = -rp0, ry = -rp1, rz = -rp2;
        float ang = sqrtf(rx * rx + ry * ry + rz * rz) + 1e-8f;
        float ax = rx / ang, ay = ry / ang, az = rz / ang;
        float K[3][3] = {{0.f, -az, ay}, {az, 0.f, -ax}, {-ay, ax, 0.f}};
        float c = cosf(ang), s = sinf(ang);
        float K2[3][3], Rm[3][3];
#pragma unroll
        for (int i = 0; i < 3; i++)
#pragma unroll
            for (int j = 0; j < 3; j++)
                K2[i][j] = K[i][0] * K[0][j] + K[i][1] * K[1][j] + K[i][2] * K[2][j];
#pragma unroll
        for (int i = 0; i < 3; i++)
#pragma unroll
            for (int j = 0; j < 3; j++)
                Rm[i][j] = (i == j ? 1.f : 0.f) + s * K[i][j] + (1.f - c) * K2[i][j];
        float t0 = lp0, t1 = lp1, t2 = lp2;
        float* M = ws + 64 + (b * 3 + k) * 12;
#pragma unroll
        for (int i = 0; i < 3; i++) {
            M[i * 4 + 0] = Rm[i][0]; M[i * 4 + 1] = Rm[i][1]; M[i * 4 + 2] = Rm[i][2];
            float tt = (i == 0 ? t0 : (i == 1 ? t1 : t2));
            M[i * 4 + 3] = tt - (Rm[i][0] * t0 + Rm[i][1] * t1 + Rm[i][2] * t2);
        }
    }
    if (tid >= 12 && tid < 36) {
        int s2 = tid - 12;
        unsigned* keys = (unsigned*)(ws + 256);
        keys[s2] = ((s2 % 6) < 3) ? fkey(BIGF) : fkey(-BIGF);
    }
}

__global__ __launch_bounds__(256) void k_minmax(const float4* __restrict__ in4,
                                                float* __restrict__ ws) {
    const int b = blockIdx.y;
    const int t = blockIdx.x * 256 + threadIdx.x;
    const size_t ib = (size_t)b * NCH * HW4 + t;
    const float* Mb = ws + 64 + b * 36;
    float4 n0 = in4[ib], n1 = in4[ib + HW4], n2 = in4[ib + 2 * HW4];
    float4 mv = in4[ib + 3 * HW4];
    float4 g0 = in4[ib + 16 * HW4], g1 = in4[ib + 17 * HW4];
    float4 g2 = in4[ib + 18 * HW4], g3 = in4[ib + 19 * HW4];
    float mn[3] = {BIGF, BIGF, BIGF}, mx[3] = {-BIGF, -BIGF, -BIGF};
#pragma unroll
    for (int k = 0; k < 4; k++) {
        float m = sigmoidf_(((const float*)&mv)[k]);
        if (!(m > THRESHF)) continue;
        float v0 = ((const float*)&g0)[k], v1 = ((const float*)&g1)[k];
        float v2 = ((const float*)&g2)[k], v3 = ((const float*)&g3)[k];
        int am = 0; float bb = v0;
        if (v1 > bb) { bb = v1; am = 1; }
        if (v2 > bb) { bb = v2; am = 2; }
        if (v3 > bb) { bb = v3; am = 3; }
        float px = 0.f, py = 0.f, pz = 0.f;
        if (am > 0) {
            const float* Mk = Mb + (am - 1) * 12;
            float a = ((const float*)&n0)[k], bq = ((const float*)&n1)[k], cq = ((const float*)&n2)[k];
            px = Mk[0] * a + Mk[1] * bq + Mk[2]  * cq + Mk[3];
            py = Mk[4] * a + Mk[5] * bq + Mk[6]  * cq + Mk[7];
            pz = Mk[8] * a + Mk[9] * bq + Mk[10] * cq + Mk[11];
        }
        mn[0] = fminf(mn[0], px); mn[1] = fminf(mn[1], py); mn[2] = fminf(mn[2], pz);
        mx[0] = fmaxf(mx[0], px); mx[1] = fmaxf(mx[1], py); mx[2] = fmaxf(mx[2], pz);
    }
    __shared__ float rmn[4][3], rmx[4][3];
    int lane = threadIdx.x & 63, wid = threadIdx.x >> 6;
#pragma unroll
    for (int i = 0; i < 3; i++) {
        float v = mn[i];
        for (int off = 32; off > 0; off >>= 1) v = fminf(v, __shfl_down(v, off, 64));
        if (lane == 0) rmn[wid][i] = v;
        float u = mx[i];
        for (int off = 32; off > 0; off >>= 1) u = fmaxf(u, __shfl_down(u, off, 64));
        if (lane == 0) rmx[wid][i] = u;
    }
    __syncthreads();
    unsigned* keys = (unsigned*)(ws + 256);
    if (threadIdx.x < 3) {
        int i = threadIdx.x;
        float v = fminf(fminf(rmn[0][i], rmn[1][i]), fminf(rmn[2][i], rmn[3][i]));
        atomicMin(&keys[b * 6 + i], fkey(v));
    } else if (threadIdx.x < 6) {
        int i = threadIdx.x - 3;
        float v = fmaxf(fmaxf(rmx[0][i], rmx[1][i]), fmaxf(rmx[2][i], rmx[3][i]));
        atomicMax(&keys[b * 6 + 3 + i], fkey(v));
    }
}

__global__ void k_prep(float* __restrict__ ws) {
    int b = threadIdx.x;
    if (b < NB) {
        const unsigned* keys = (const unsigned*)(ws + 256);
        float l0 = funkey(keys[b * 6 + 0]), l1 = funkey(keys[b * 6 + 1]), l2 = funkey(keys[b * 6 + 2]);
        float u0 = funkey(keys[b * 6 + 3]), u1 = funkey(keys[b * 6 + 4]), u2 = funkey(keys[b * 6 + 5]);
        float scale = fmaxf(u0 - l0, fmaxf(u1 - l1, u2 - l2));
        float safe = (scale == 0.f) ? 1.f : scale;
        float* pr = ws + 288 + b * 8;
        pr[0] = l0; pr[1] = l1; pr[2] = l2; pr[3] = safe;
        pr[4] = (scale != 0.f) ? 1.f : 0.f;
    }
}

__global__ __launch_bounds__(256) void k_main(const float4* __restrict__ in4,
                                              float4* __restrict__ out4,
                                              float* __restrict__ occ,
                                              const float* __restrict__ ws) {
    __shared__ float accz[64];   // aggregator for the shared amax==0 voxel
    if (threadIdx.x < 64) accz[threadIdx.x] = 0.f;
    __syncthreads();
    const int b = blockIdx.y;
    const int t = blockIdx.x * 256 + threadIdx.x;
    const size_t ib = (size_t)b * NCH * HW4 + t;
    const size_t ob = (size_t)b * OCH * HW4 + t;
    const float* Mb = ws + 64 + b * 36;
    const float* pr = ws + 288 + b * 8;
    float l0 = pr[0], l1 = pr[1], l2 = pr[2], safe = pr[3];
    bool flag = pr[4] != 0.f;

    float4 n0 = in4[ib];              out4[ob] = n0;
    float4 n1 = in4[ib + HW4];        out4[ob + HW4] = n1;
    float4 n2 = in4[ib + 2 * HW4];    out4[ob + 2 * HW4] = n2;
    float4 mv = in4[ib + 3 * HW4];    out4[ob + 3 * HW4] = mv;
#pragma unroll
    for (int c = 4; c < 16; c++) { float4 v = in4[ib + (size_t)c * HW4]; out4[ob + (size_t)c * HW4] = v; }
    float4 g0 = in4[ib + 16 * HW4];   out4[ob + 16 * HW4] = g0;
    float4 g1 = in4[ib + 17 * HW4];   out4[ob + 17 * HW4] = g1;
    float4 g2 = in4[ib + 18 * HW4];   out4[ob + 18 * HW4] = g2;
    float4 g3 = in4[ib + 19 * HW4];   out4[ob + 19 * HW4] = g3;
    { float4 v = in4[ib + 20 * HW4]; out4[ob + 20 * HW4] = v;
      v = in4[ib + 21 * HW4];        out4[ob + 21 * HW4] = v; }

    int flat[4]; bool msk[4], spec[4];
    float4 pm0, pm1, pm2;
    float* pm0f = (float*)&pm0; float* pm1f = (float*)&pm1; float* pm2f = (float*)&pm2;
#pragma unroll
    for (int k = 0; k < 4; k++) {
        float m = sigmoidf_(((const float*)&mv)[k]);
        bool masked = m > THRESHF;
        float v0 = ((const float*)&g0)[k], v1 = ((const float*)&g1)[k];
        float v2 = ((const float*)&g2)[k], v3 = ((const float*)&g3)[k];
        int am = 0; float bb = v0;
        if (v1 > bb) { bb = v1; am = 1; }
        if (v2 > bb) { bb = v2; am = 2; }
        if (v3 > bb) { bb = v3; am = 3; }
        float px = 0.f, py = 0.f, pz = 0.f;
        if (am > 0) {
            const float* Mk = Mb + (am - 1) * 12;
            float a = ((const float*)&n0)[k], bq = ((const float*)&n1)[k], cq = ((const float*)&n2)[k];
            px = Mk[0] * a + Mk[1] * bq + Mk[2]  * cq + Mk[3];
            py = Mk[4] * a + Mk[5] * bq + Mk[6]  * cq + Mk[7];
            pz = Mk[8] * a + Mk[9] * bq + Mk[10] * cq + Mk[11];
        }
        float qx, qy, qz;
        if (flag) { qx = (px - l0) / safe; qy = (py - l1) / safe; qz = (pz - l2) / safe; }
        else      { qx = px; qy = py; qz = pz; }
        float ox = masked ? qx : 0.f, oy = masked ? qy : 0.f, oz = masked ? qz : 0.f;
        pm0f[k] = ox; pm1f[k] = oy; pm2f[k] = oz;
        msk[k] = masked;
        spec[k] = masked && (am == 0);
        int fl = 0;
        if (masked) {
            int vx = (int)floorf(ox * 32.f); vx = vx < 0 ? 0 : (vx > 31 ? 31 : vx);
            int vy = (int)floorf(oy * 32.f); vy = vy < 0 ? 0 : (vy > 31 ? 31 : vy);
            int vz = (int)floorf(oz * 32.f); vz = vz < 0 ? 0 : (vz > 31 ? 31 : vz);
            fl = vx * 1024 + vy * 32 + vz;
        }
        flat[k] = fl;
    }
    out4[ob + (size_t)86 * HW4] = pm0;
    out4[ob + (size_t)87 * HW4] = pm1;
    out4[ob + (size_t)88 * HW4] = pm2;

    bool anySpec = spec[0] | spec[1] | spec[2] | spec[3];
    bool glb[4];
#pragma unroll
    for (int k = 0; k < 4; k++) glb[k] = msk[k] && !spec[k];
    bool anyGlob = glb[0] | glb[1] | glb[2] | glb[3];
    float* occb = occ + ((size_t)(b * 64) << 15);
#pragma unroll 4
    for (int c = 22; c < 86; c++) {
        float4 v = in4[ib + (size_t)c * HW4];
        out4[ob + (size_t)c * HW4] = v;
        const float* vf = (const float*)&v;
        int f = c - 22;
        if (anySpec) {
            float sv = 0.f;
#pragma unroll
            for (int k = 0; k < 4; k++) if (spec[k]) sv += vf[k];
            atomicAdd(&accz[f], sv);
        }
        if (anyGlob) {
            float* of = occb + ((size_t)f << 15);
#pragma unroll
            for (int k = 0; k < 4; k++) if (glb[k]) atomicAdd(&of[flat[k]], vf[k]);
        }
    }
    __syncthreads();
    if (threadIdx.x < 64) {
        float v = accz[threadIdx.x];
        if (v != 0.f) {
            float q0 = flag ? (0.f - l0) / safe : 0.f;
            float q1 = flag ? (0.f - l1) / safe : 0.f;
            float q2 = flag ? (0.f - l2) / safe : 0.f;
            int vx = (int)floorf(q0 * 32.f); vx = vx < 0 ? 0 : (vx > 31 ? 31 : vx);
            int vy = (int)floorf(q1 * 32.f); vy = vy < 0 ? 0 : (vy > 31 ? 31 : vy);
            int vz = (int)floorf(q2 * 32.f); vz = vz < 0 ? 0 : (vz > 31 ? 31 : vz);
            int fl = vx * 1024 + vy * 32 + vz;
            atomicAdd(&occb[((size_t)threadIdx.x << 15) + fl], v);
        }
    }
}

extern "C" void kernel_launch(void* const* d_in, const int* in_sizes, int n_in,
                              void* d_out, int out_size, void* d_ws, size_t ws_size,
                              hipStream_t stream) {
    const float* in = (const float*)d_in[0];
    float* out = (float*)d_out;
    float* ws = (float*)d_ws;
    float* occ = out + (size_t)NB * OCH * 76800;   // 27,340,800

    hipMemsetAsync(ws, 0, 64 * sizeof(float), stream);
    hipMemsetAsync(occ, 0, (size_t)NB * 64 * 32768 * sizeof(float), stream);

    dim3 grid(75, NB);
    k_votes <<<grid, 256, 0, stream>>>((const float4*)in, ws);
    k_build <<<1, 64, 0, stream>>>(ws);
    k_minmax<<<grid, 256, 0, stream>>>((const float4*)in, ws);
    k_prep  <<<1, 64, 0, stream>>>(ws);
    k_main  <<<grid, 256, 0, stream>>>((const float4*)in, (float4*)out, occ, ws);
}